// Round 1
// baseline (197.959 us; speedup 1.0000x reference)
//
#include <hip/hip_runtime.h>

// Problem: out[b,:] = softmax_s( enc[b,s,:] . w2 ),  w2[k] = sum_h v[h]*W[h,2H+k].
// hidden/bias contributions are constant along s -> cancel under softmax(axis=1).
// HBM floor: read enc once = 64*512*1024*4 B = 134 MB (~21 us at 6.3 TB/s).
// Measured dur_us also contains ~130-140 us of harness reset (536 MB ws poison
// fill + 147 MB input restore) visible as fillBufferAligned dispatches.
//
// R1 changes (no counters this round -- structural reasoning):
//  A: 128-B-aligned k-tiles (32 consecutive floats/segment, was 64 B) + h split
//     over 4 block-groups -> 128 blocks, exact 4 MB fetch (was ~8 MB over 64 CUs).
//     Partials [4][1024] combined for free in B's one-time w2 hoist.
//  B: hoist w2 into 16 VGPRs once per wave; 4 contiguous rows per wave
//     (16 KB contiguous; 16 independent nt loads in flight; w2 not re-read
//     per row; 1 reduce+store per 4 KB unchanged but amortized addressing).

#define HID 1024
#define BB  64
#define SS  512
#define W3H 3072

typedef float floatx4 __attribute__((ext_vector_type(4)));

// Kernel A: partial fold. Grid 128 = 32 k-tiles x 4 h-quarters, 1024 thr.
// Block (kt, hq): k in [32*kt, 32*kt+32), h in [256*hq, 256*hq+256).
// Thread = (hg = t>>5 in [0,32), kl = t&31); each thread sums 8 h-values.
// Wave = 2 h-rows x 32 consecutive k = two full 128-B lines per load instr.
// Output: w2part[hq][k]; B sums the 4 quarters when hoisting w2.
__global__ __launch_bounds__(1024) void wfold_kernel(
        const float* __restrict__ W, const float* __restrict__ v,
        float* __restrict__ w2part) {
    __shared__ float part[32][33];
    const int kl = threadIdx.x & 31;
    const int hg = threadIdx.x >> 5;            // 0..31
    const int kt = blockIdx.x & 31;             // k-tile
    const int hq = blockIdx.x >> 5;             // h-quarter
    const int k  = kt * 32 + kl;
    const int h0 = hq * 256 + hg * 8;
    float acc = 0.0f;
    #pragma unroll
    for (int h = h0; h < h0 + 8; ++h)
        acc += v[h] * W[(size_t)h * W3H + 2 * HID + k];
    part[hg][kl] = acc;
    __syncthreads();
    // tree-reduce over hg: 32 -> 16 -> ... -> 1
    for (int half = 16; half >= 1; half >>= 1) {
        if (hg < half) part[hg][kl] += part[hg + half][kl];
        __syncthreads();
    }
    if (threadIdx.x < 32) w2part[hq * HID + k] = part[0][kl];
}

// Kernel B: scores[r] = dot(enc[r,:], w2). 2048 blocks x 256 threads.
// Each wave: hoist w2 (sum of 4 h-quarter partials) into 16 VGPRs once,
// then 4 contiguous rows, 16B nontemporal loads (enc streamed once).
__global__ __launch_bounds__(256) void scores_kernel(
        const floatx4* __restrict__ enc4, const floatx4* __restrict__ w2p4,
        float* __restrict__ scores) {
    const int wave = threadIdx.x >> 6;
    const int lane = threadIdx.x & 63;
    const int wid  = blockIdx.x * 4 + wave;         // wave id in [0, 8192)

    floatx4 w[4];
    #pragma unroll
    for (int i = 0; i < 4; ++i) {
        floatx4 s = w2p4[0 * 256 + i * 64 + lane];
        #pragma unroll
        for (int q = 1; q < 4; ++q)
            s += w2p4[q * 256 + i * 64 + lane];
        w[i] = s;
    }

    const floatx4* base = enc4 + (size_t)wid * 4 * (HID / 4);
    float acc[4];
    #pragma unroll
    for (int j = 0; j < 4; ++j) {
        acc[j] = 0.0f;
        #pragma unroll
        for (int i = 0; i < 4; ++i) {
            floatx4 e = __builtin_nontemporal_load(&base[j * 256 + i * 64 + lane]);
            acc[j] += e.x * w[i].x + e.y * w[i].y + e.z * w[i].z + e.w * w[i].w;
        }
    }
    #pragma unroll
    for (int j = 0; j < 4; ++j) {
        float a = acc[j];
        #pragma unroll
        for (int off = 32; off > 0; off >>= 1)
            a += __shfl_down(a, off);
        if (lane == 0) scores[wid * 4 + j] = a;
    }
}

// Kernel C: per-b softmax over 512 scores. One block of 512 threads per b.
__global__ __launch_bounds__(512) void softmax_kernel(
        const float* __restrict__ scores, float* __restrict__ out) {
    __shared__ float red[8];
    const int b = blockIdx.x;
    const int t = threadIdx.x;
    const int wave = t >> 6, lane = t & 63;

    float x = scores[b * SS + t];

    float m = x;
    #pragma unroll
    for (int off = 32; off > 0; off >>= 1)
        m = fmaxf(m, __shfl_down(m, off));
    if (lane == 0) red[wave] = m;
    __syncthreads();
    if (t == 0) {
        float mm = red[0];
        #pragma unroll
        for (int i = 1; i < 8; ++i) mm = fmaxf(mm, red[i]);
        red[0] = mm;
    }
    __syncthreads();
    m = red[0];
    __syncthreads();

    float e = expf(x - m);

    float s = e;
    #pragma unroll
    for (int off = 32; off > 0; off >>= 1)
        s += __shfl_down(s, off);
    if (lane == 0) red[wave] = s;
    __syncthreads();
    if (t == 0) {
        float tot = 0.0f;
        #pragma unroll
        for (int i = 0; i < 8; ++i) tot += red[i];
        red[0] = tot;
    }
    __syncthreads();
    out[b * SS + t] = e / red[0];
}

extern "C" void kernel_launch(void* const* d_in, const int* in_sizes, int n_in,
                              void* d_out, int out_size, void* d_ws, size_t ws_size,
                              hipStream_t stream) {
    // inputs: hidden [2,64,1024] (unused), encoder_outputs [64,512,1024],
    //         W [1024,3072], b [1024] (unused), v [1024]
    const float* enc = (const float*)d_in[1];
    const float* W   = (const float*)d_in[2];
    const float* v   = (const float*)d_in[4];
    float* out = (float*)d_out;

    float* w2part = (float*)d_ws;         // [4][1024] floats
    float* scores = w2part + 4 * HID;     // 32768 floats

    wfold_kernel<<<128, 1024, 0, stream>>>(W, v, w2part);

    scores_kernel<<<(BB * SS) / 16, 256, 0, stream>>>(
        (const floatx4*)enc, (const floatx4*)w2part, scores);

    softmax_kernel<<<BB, 512, 0, stream>>>(scores, out);
}